// Round 16
// baseline (146.075 us; speedup 1.0000x reference)
//
#include <hip/hip_runtime.h>

typedef unsigned short u16;
typedef unsigned int u32;
typedef __attribute__((ext_vector_type(4))) unsigned short u16x4;
typedef __attribute__((ext_vector_type(8))) unsigned short u16x8;
typedef __attribute__((ext_vector_type(8))) __bf16 bf16x8;
typedef __attribute__((ext_vector_type(4))) float f32x4;
typedef __attribute__((ext_vector_type(16))) float f32x16;

#define SEQ 2048
#define DMODEL 1024
#define LDP 3072
#define MM (DMODEL * DMODEL)
#define SC 0.18033688f  // (1/8) * log2(e)

__device__ __forceinline__ u16 f2bf(float f) {
  unsigned u = __builtin_bit_cast(unsigned, f);
  u = (u + 0x7fffu + ((u >> 16) & 1u)) >> 16;
  return (u16)u;
}

__device__ __forceinline__ u32 cvtpk(float lo, float hi) {
  u32 r;
  asm volatile("v_cvt_pk_bf16_f32 %0, %1, %2" : "=v"(r) : "v"(lo), "v"(hi));
  return r;
}

__device__ __forceinline__ float fexp2(float x) {
#if __has_builtin(__builtin_amdgcn_exp2f)
  return __builtin_amdgcn_exp2f(x);
#else
  return exp2f(x);
#endif
}

__device__ __forceinline__ bf16x8 ldbf8(const u16* p) {
  return __builtin_bit_cast(bf16x8, *(const u16x8*)p);
}
__device__ __forceinline__ bf16x8 ldbf8c(const char* p) {
  return __builtin_bit_cast(bf16x8, *(const u16x8*)p);
}

__device__ __forceinline__ f32x4 mfma16(bf16x8 a, bf16x8 b, f32x4 c) {
  return __builtin_amdgcn_mfma_f32_16x16x32_bf16(a, b, c, 0, 0, 0);
}
__device__ __forceinline__ f32x16 mfma32(bf16x8 a, bf16x8 b, f32x16 c) {
  return __builtin_amdgcn_mfma_f32_32x32x16_bf16(a, b, c, 0, 0, 0);
}

__device__ __forceinline__ void gl16(const void* g, void* l) {
  __builtin_amdgcn_global_load_lds(
      (__attribute__((address_space(1))) void*)(size_t)g,
      (__attribute__((address_space(3))) void*)l, 16, 0, 0);
}

// ----------------- fp32 -> bf16 cast (single merged kernel) -----------------
__global__ void cast_all_k(const float* __restrict__ q, const float* __restrict__ k,
                           const float* __restrict__ v, const float* __restrict__ wq,
                           const float* __restrict__ wk, const float* __restrict__ wv,
                           const float* __restrict__ wo, u16* __restrict__ dq,
                           u16* __restrict__ dk, u16* __restrict__ dv,
                           u16* __restrict__ wqkv, u16* __restrict__ wob) {
  int b = blockIdx.x;
  const float* s;
  u16* d;
  if (b < 6144) {  // q,k,v: 2048 blocks each
    const int z = b >> 11;
    s = z == 0 ? q : z == 1 ? k : v;
    d = z == 0 ? dq : z == 1 ? dk : dv;
    b &= 2047;
  } else {  // weights: 512 blocks each
    const int z = (b - 6144) >> 9;
    s = z == 0 ? wq : z == 1 ? wk : z == 2 ? wv : wo;
    d = z < 3 ? wqkv + (size_t)z * MM : wob;
    b = (b - 6144) & 511;
  }
  const size_t i = ((size_t)b * blockDim.x + threadIdx.x) * 8;
  const float4 a = *(const float4*)(s + i);
  const float4 c = *(const float4*)(s + i + 4);
  u16x8 o;
  o[0] = f2bf(a.x); o[1] = f2bf(a.y); o[2] = f2bf(a.z); o[3] = f2bf(a.w);
  o[4] = f2bf(c.x); o[5] = f2bf(c.y); o[6] = f2bf(c.z); o[7] = f2bf(c.w);
  *(u16x8*)(d + i) = o;
}

// ----------------- GEMM: C = A @ B^T + bias (BK=64, swizzled gl16) ---------
// LDS arrays declared in the KERNEL and passed in (round-14 lesson: per-
// instantiation static __shared__ doubles LDS -> occupancy wall).
template <int OMODE>
__device__ __forceinline__ void gemm_bt_body(u16* __restrict__ As,
                                             u16* __restrict__ Bs,
                                             const u16* __restrict__ A,
                                             const u16* __restrict__ Bw,
                                             const float* __restrict__ bias,
                                             void* __restrict__ Cv, const int K,
                                             const int ldc, const int ncol0,
                                             const int m0, const int n0,
                                             const float osc) {
  const int tid = threadIdx.x;
  const int lane = tid & 63;
  const int w = tid >> 6;
  const int l15 = lane & 15;
  const int lg = lane >> 4;

  f32x4 acc[4][4] = {};

  const int arow = (w >> 1) * 64 + l15;
  const int brow = (w & 1) * 64 + l15;
  const int swz = (l15 & 7) << 4;

  const u16* Ags[4];
  const u16* Bgs[4];
#pragma unroll
  for (int j = 0; j < 4; ++j) {
    const int c = w * 64 + lane + j * 256;
    const int row = c >> 3;
    const int sc = ((c & 7) ^ (row & 7)) * 8;
    Ags[j] = A + (size_t)(m0 + row) * K + sc;
    Bgs[j] = Bw + (size_t)(n0 + row) * K + sc;
  }

  for (int k0 = 0; k0 < K; k0 += 64) {
    __syncthreads();  // prior iter's LDS reads done
#pragma unroll
    for (int j = 0; j < 4; ++j) {
      gl16(Ags[j] + k0, (char*)As + (w + j * 4) * 1024);
      gl16(Bgs[j] + k0, (char*)Bs + (w + j * 4) * 1024);
    }
    __syncthreads();  // barrier drains vmcnt -> staged data visible
#pragma unroll
    for (int kk = 0; kk < 2; ++kk) {
      const int cb = (kk * 64 + lg * 16) ^ swz;
      bf16x8 af[4], bfv[4];
#pragma unroll
      for (int t = 0; t < 4; ++t) {
        af[t] = ldbf8c((char*)As + (arow + t * 16) * 128 + cb);
        bfv[t] = ldbf8c((char*)Bs + (brow + t * 16) * 128 + cb);
      }
      __builtin_amdgcn_s_setprio(1);
#pragma unroll
      for (int i = 0; i < 4; ++i)
#pragma unroll
        for (int j = 0; j < 4; ++j) acc[i][j] = mfma16(af[i], bfv[j], acc[i][j]);
      __builtin_amdgcn_s_setprio(0);
    }
  }

  const int mrow = (w >> 1) * 64 + lg * 4;
  const int ncol = (w & 1) * 64 + l15;
#pragma unroll
  for (int j = 0; j < 4; ++j) {
    const int gn = n0 + ncol + j * 16;
    const float bia = bias[gn];
#pragma unroll
    for (int i = 0; i < 4; ++i) {
      const int gmb = m0 + mrow + i * 16;
#pragma unroll
      for (int r = 0; r < 4; ++r) {
        const float val = (acc[i][j][r] + bia) * osc;
        const int gm = gmb + r;
        if (OMODE == 0) {
          ((float*)Cv)[(size_t)gm * ldc + gn] = val;
        } else if (OMODE == 1) {
          ((u16*)Cv)[(size_t)gm * ldc + ncol0 + gn] = f2bf(val);
        } else {
          const int bb = gm >> 11, ss = gm & 2047;
          const int ssp = (ss & ~12) | ((ss & 4) << 1) | ((ss & 8) >> 1);
          const int hh = gn >> 6, dd = gn & 63;
          ((u16*)Cv)[(((size_t)(bb * 16 + hh) * 64 + dd) << 11) + ssp] = f2bf(val);
        }
      }
    }
  }
}

// XCD-chunked QKV projections (768 blocks; xcd = b&7).
__global__ __launch_bounds__(256, 3) void gemm_qkv_k(
    const u16* __restrict__ qb, const u16* __restrict__ kb,
    const u16* __restrict__ vb, const u16* __restrict__ wqkv,
    const float* __restrict__ bq, const float* __restrict__ bk,
    const float* __restrict__ bv, u16* __restrict__ proj, u16* __restrict__ vtb) {
  __shared__ u16 As[128 * 64];  // shared across both instantiations below
  __shared__ u16 Bs[128 * 64];
  const int b = blockIdx.x;
  const int xcd = b & 7;
  const int i = b >> 3;
  const int z = i >> 5;
  const int j = i & 31;
  const int m0 = (xcd * 4 + (j >> 3)) * 128;
  const int n0 = (j & 7) * 128;
  if (z == 2)
    gemm_bt_body<2>(As, Bs, vb, wqkv + 2 * (size_t)MM, bv, vtb, DMODEL, 0, 0,
                    m0, n0, 1.0f);
  else
    gemm_bt_body<1>(As, Bs, z == 0 ? qb : kb, wqkv + (size_t)z * MM,
                    z == 0 ? bq : bk, proj, DMODEL, LDP, z * DMODEL, m0, n0,
                    z == 0 ? SC : 1.0f);
}

__global__ __launch_bounds__(256, 3) void gemm_o_k(const u16* __restrict__ attnb,
                                                   const u16* __restrict__ wob,
                                                   const float* __restrict__ bo,
                                                   float* __restrict__ out) {
  __shared__ u16 As[128 * 64];
  __shared__ u16 Bs[128 * 64];
  const int b = blockIdx.x;
  const int xcd = b & 7;
  const int i = b >> 3;
  const int m0 = (xcd * 4 + (i >> 3)) * 128;
  const int n0 = (i & 7) * 128;
  gemm_bt_body<0>(As, Bs, attnb, wob, bo, out, DMODEL, DMODEL, 0, m0, n0, 1.0f);
}

// ----------------- flash attention: split-KV, q-reuse, 128-kv mega-iter ----
// 256 blocks x 512 threads (1/CU). 2 kv-groups x 4 waves; wave owns 64 q
// (2 tiles). Each mega-iter stages the NEXT 128 kv (2 sub-tiles, 8 gl16)
// then computes BOTH sub-tiles of the current 128 kv -> ONE barrier per
// 128 kv (8 barriers total vs 16), attacking the measured ~4.5k cyc/iter
// lockstep overhead. LDS 128 KB: per group [2 buf][2 sub] K + V.
__global__ __launch_bounds__(512, 2) void attn_k(const u16* __restrict__ proj,
                                                 const u16* __restrict__ vtb,
                                                 u16* __restrict__ outa) {
  __shared__ __align__(16) char smem[131072];
  const int b = blockIdx.x;
  const int slot = b >> 3;                 // 0..31
  const int bh = (b & 7) * 4 + (slot >> 3);
  const int qB = (slot & 7) * 256;
  const int tid = threadIdx.x;
  const int lane = tid & 63;
  const int w = tid >> 6;
  const int g = w >> 2;        // kv-half group
  const int wg = w & 3;        // wave within group
  const size_t rb = (size_t)(bh >> 4) * SEQ;
  const int h = bh & 15;
  const int l31 = lane & 31;
  const int hi = lane >> 5;
  const int swzk = (l31 & 7) << 4;

  // LDS: group g at g*65536. K: [2 buf][2 sub][8192] at 0; V same at 32768.
  char* const gbase = smem + g * 65536;

  // Q B-frags for both q-tiles (pre-scaled by SC)
  const int qW = qB + wg * 64;
  const u16* qpA = proj + (rb + qW + l31) * LDP + h * 64 + hi * 8;
  const u16* qpB = qpA + (size_t)32 * LDP;
  bf16x8 qfA[4], qfB[4];
#pragma unroll
  for (int km = 0; km < 4; ++km) {
    qfA[km] = ldbf8(qpA + km * 16);
    qfB[km] = ldbf8(qpB + km * 16);
  }

  // staging constants (pre-swizzled source; linear LDS dest)
  const int cxe = ((lane & 7) ^ (lane >> 3)) * 8;  // element offset
  const int row0 = wg * 16 + (lane >> 3);          // j=0 row
  const int row1 = row0 + 8;                       // j=1 row
  const u16* kg = proj + rb * LDP + DMODEL + h * 64;  // K rows, stride LDP
  const u16* vg = vtb + (size_t)bh * 64 * SEQ;        // V^T rows [d][s-perm]
  const int kvbase = g * (SEQ / 2);
  const u16* ks0 = kg + (size_t)(kvbase + row0) * LDP + cxe;
  const u16* ks1 = kg + (size_t)(kvbase + row1) * LDP + cxe;
  const u16* vs0 = vg + (size_t)row0 * SEQ + kvbase + cxe;
  const u16* vs1 = vg + (size_t)row1 * SEQ + kvbase + cxe;

#define STAGE(P, KV)                                                     \
  {                                                                      \
    char* kb_ = gbase + (P) * 16384;                                     \
    char* vb_ = gbase + 32768 + (P) * 16384;                             \
    gl16(ks0 + (size_t)(KV) * LDP, kb_ + (wg * 2 + 0) * 1024);           \
    gl16(ks1 + (size_t)(KV) * LDP, kb_ + (wg * 2 + 1) * 1024);           \
    gl16(ks0 + (size_t)((KV) + 64) * LDP, kb_ + 8192 + (wg * 2 + 0) * 1024); \
    gl16(ks1 + (size_t)((KV) + 64) * LDP, kb_ + 8192 + (wg * 2 + 1) * 1024); \
    gl16(vs0 + (KV), vb_ + (wg * 2 + 0) * 1024);                         \
    gl16(vs1 + (KV), vb_ + (wg * 2 + 1) * 1024);                         \
    gl16(vs0 + (KV) + 64, vb_ + 8192 + (wg * 2 + 0) * 1024);             \
    gl16(vs1 + (KV) + 64, vb_ + 8192 + (wg * 2 + 1) * 1024);             \
  }

  f32x16 oaA0 = {}, oaA1 = {}, oaB0 = {}, oaB1 = {};
  float lrunA = 0.f, lrunB = 0.f;
  int p = 0;

  STAGE(0, 0);
  __syncthreads();

  for (int it = 0; it < SEQ / 256; ++it) {  // 8 mega-iters (128 kv each)
    if (it + 1 < SEQ / 256) STAGE(p ^ 1, (it + 1) * 128);
#pragma unroll
    for (int half = 0; half < 2; ++half) {
      const char* kp = gbase + p * 16384 + half * 8192;
      const char* vp = gbase + 32768 + p * 16384 + half * 8192;
      // ---- QK^T: each K-frag feeds both q-tiles ----
      f32x16 sA0 = {}, sA1 = {}, sB0 = {}, sB1 = {};
      __builtin_amdgcn_s_setprio(1);
#pragma unroll
      for (int km = 0; km < 4; ++km) {
        const int co = (km * 32 + hi * 16) ^ swzk;
        const bf16x8 k0 = ldbf8c(kp + l31 * 128 + co);
        const bf16x8 k1 = ldbf8c(kp + (32 + l31) * 128 + co);
        sA0 = mfma32(k0, qfA[km], sA0);
        sB0 = mfma32(k0, qfB[km], sB0);
        sA1 = mfma32(k1, qfA[km], sA1);
        sB1 = mfma32(k1, qfB[km], sB1);
      }
      __builtin_amdgcn_s_setprio(0);

      // ---- P = exp2(s); unnormalized row sums ----
#pragma unroll
      for (int r = 0; r < 16; ++r) sA0[r] = fexp2(sA0[r]);
#pragma unroll
      for (int r = 0; r < 16; ++r) sA1[r] = fexp2(sA1[r]);
#pragma unroll
      for (int r = 0; r < 16; ++r) sB0[r] = fexp2(sB0[r]);
#pragma unroll
      for (int r = 0; r < 16; ++r) sB1[r] = fexp2(sB1[r]);
#define SUM16(V)                                                        \
      ((((V[0] + V[1]) + (V[2] + V[3])) + ((V[4] + V[5]) + (V[6] + V[7]))) + \
       (((V[8] + V[9]) + (V[10] + V[11])) + ((V[12] + V[13]) + (V[14] + V[15]))))
      float rsA = SUM16(sA0) + SUM16(sA1);
      float rsB = SUM16(sB0) + SUM16(sB1);
#undef SUM16
      rsA += __shfl_xor(rsA, 32);
      rsB += __shfl_xor(rsB, 32);
      lrunA += rsA;
      lrunB += rsB;

      // ---- PV: V frags are b128 (permuted storage); feed both q-tiles ----
      __builtin_amdgcn_s_setprio(1);
#define PCHUNK2(SA, SB, G, M)                                            \
      {                                                                  \
        u16x8 pbuA, pbuB;                                                \
        ((u32*)&pbuA)[0] = cvtpk(SA[G + 0], SA[G + 1]);                  \
        ((u32*)&pbuA)[1] = cvtpk(SA[G + 2], SA[G + 3]);                  \
        ((u32*)&pbuA)[2] = cvtpk(SA[G + 4], SA[G + 5]);                  \
        ((u32*)&pbuA)[3] = cvtpk(SA[G + 6], SA[G + 7]);                  \
        ((u32*)&pbuB)[0] = cvtpk(SB[G + 0], SB[G + 1]);                  \
        ((u32*)&pbuB)[1] = cvtpk(SB[G + 2], SB[G + 3]);                  \
        ((u32*)&pbuB)[2] = cvtpk(SB[G + 4], SB[G + 5]);                  \
        ((u32*)&pbuB)[3] = cvtpk(SB[G + 6], SB[G + 7]);                  \
        const bf16x8 pbA = __builtin_bit_cast(bf16x8, pbuA);             \
        const bf16x8 pbB = __builtin_bit_cast(bf16x8, pbuB);             \
        const int vc = ((M) * 32 + hi * 16) ^ swzk;                      \
        const bf16x8 v0 = ldbf8c(vp + l31 * 128 + vc);                   \
        const bf16x8 v1 = ldbf8c(vp + (32 + l31) * 128 + vc);            \
        oaA0 = mfma32(v0, pbA, oaA0);                                    \
        oaB0 = mfma32(v0, pbB, oaB0);                                    \
        oaA1 = mfma32(v1, pbA, oaA1);                                    \
        oaB1 = mfma32(v1, pbB, oaB1);                                    \
      }
      PCHUNK2(sA0, sB0, 0, 0)
      PCHUNK2(sA0, sB0, 8, 1)
      PCHUNK2(sA1, sB1, 0, 2)
      PCHUNK2(sA1, sB1, 8, 3)
#undef PCHUNK2
      __builtin_amdgcn_s_setprio(0);
    }
    __syncthreads();  // drains vmcnt (next tile landed) + read/write fence
    p ^= 1;
  }
#undef STAGE

  // ---- two-pass merge of group B into group A (exact: pure adds) ----
  float* sc = (float*)smem;
  const int col = wg * 64 + lane;  // 0..255 within group
  if (g == 1) {
#pragma unroll
    for (int r = 0; r < 16; ++r) sc[r * 256 + col] = oaA0[r];
#pragma unroll
    for (int r = 0; r < 16; ++r) sc[(16 + r) * 256 + col] = oaA1[r];
    sc[32 * 256 + col] = lrunA;
  }
  __syncthreads();
  if (g == 0) {
#pragma unroll
    for (int r = 0; r < 16; ++r) oaA0[r] += sc[r * 256 + col];
#pragma unroll
    for (int r = 0; r < 16; ++r) oaA1[r] += sc[(16 + r) * 256 + col];
    lrunA += sc[32 * 256 + col];
  }
  __syncthreads();
  if (g == 1) {
#pragma unroll
    for (int r = 0; r < 16; ++r) sc[r * 256 + col] = oaB0[r];
#pragma unroll
    for (int r = 0; r < 16; ++r) sc[(16 + r) * 256 + col] = oaB1[r];
    sc[32 * 256 + col] = lrunB;
  }
  __syncthreads();
  if (g == 0) {
#pragma unroll
    for (int r = 0; r < 16; ++r) oaB0[r] += sc[r * 256 + col];
#pragma unroll
    for (int r = 0; r < 16; ++r) oaB1[r] += sc[(16 + r) * 256 + col];
    lrunB += sc[32 * 256 + col];

    // ---- epilogue: O^T[d][q] -> attnb[q][h*64+d], both q-tiles ----
    const float invA = 1.0f / lrunA;
    u16* orowA = outa + (rb + qW + l31) * DMODEL + h * 64 + hi * 4;
#pragma unroll
    for (int gg = 0; gg < 4; ++gg) {
      u16x4 st0, st1;
      ((u32*)&st0)[0] = cvtpk(oaA0[4 * gg + 0] * invA, oaA0[4 * gg + 1] * invA);
      ((u32*)&st0)[1] = cvtpk(oaA0[4 * gg + 2] * invA, oaA0[4 * gg + 3] * invA);
      *(u16x4*)(orowA + 8 * gg) = st0;
      ((u32*)&st1)[0] = cvtpk(oaA1[4 * gg + 0] * invA, oaA1[4 * gg + 1] * invA);
      ((u32*)&st1)[1] = cvtpk(oaA1[4 * gg + 2] * invA, oaA1[4 * gg + 3] * invA);
      *(u16x4*)(orowA + 32 + 8 * gg) = st1;
    }
    const float invB = 1.0f / lrunB;
    u16* orowB = orowA + (size_t)32 * DMODEL;
#pragma unroll
    for (int gg = 0; gg < 4; ++gg) {
      u16x4 st0, st1;
      ((u32*)&st0)[0] = cvtpk(oaB0[4 * gg + 0] * invB, oaB0[4 * gg + 1] * invB);
      ((u32*)&st0)[1] = cvtpk(oaB0[4 * gg + 2] * invB, oaB0[4 * gg + 3] * invB);
      *(u16x4*)(orowB + 8 * gg) = st0;
      ((u32*)&st1)[0] = cvtpk(oaB1[4 * gg + 0] * invB, oaB1[4 * gg + 1] * invB);
      ((u32*)&st1)[1] = cvtpk(oaB1[4 * gg + 2] * invB, oaB1[4 * gg + 3] * invB);
      *(u16x4*)(orowB + 32 + 8 * gg) = st1;
    }
  }
}

extern "C" void kernel_launch(void* const* d_in, const int* in_sizes, int n_in,
                              void* d_out, int out_size, void* d_ws, size_t ws_size,
                              hipStream_t stream) {
  const float* q  = (const float*)d_in[0];
  const float* k  = (const float*)d_in[1];
  const float* v  = (const float*)d_in[2];
  const float* wq = (const float*)d_in[3];
  const float* bq = (const float*)d_in[4];
  const float* wk = (const float*)d_in[5];
  const float* bk = (const float*)d_in[6];
  const float* wv = (const float*)d_in[7];
  const float* bv = (const float*)d_in[8];
  const float* wo = (const float*)d_in[9];
  const float* bo = (const float*)d_in[10];

  const size_t NTOK = (size_t)2 * SEQ;
  const size_t NELE = NTOK * DMODEL;
  u16* qb    = (u16*)d_ws;
  u16* kb    = qb + NELE;
  u16* vb    = kb + NELE;
  u16* wqkv  = vb + NELE;
  u16* wob   = wqkv + 3 * (size_t)MM;
  u16* projb = wob + (size_t)MM;          // [4096][3072] bf16 (Q,K sections)
  u16* vtb   = projb + NTOK * LDP;        // [32 bh][64 d][2048 s-perm] bf16
  u16* attnb = qb;  // qb dead after projections -> reuse

  cast_all_k<<<8192, 256, 0, stream>>>(q, k, v, wq, wk, wv, wo, qb, kb, vb,
                                       wqkv, wob);
  gemm_qkv_k<<<768, 256, 0, stream>>>(qb, kb, vb, wqkv, bq, bk, bv, projb, vtb);
  attn_k<<<256, 512, 0, stream>>>(projb, vtb, attnb);
  gemm_o_k<<<256, 256, 0, stream>>>(attnb, wob, bo, (float*)d_out);
}

// Round 17
// 116.470 us; speedup vs baseline: 1.2542x; 1.2542x over previous
//
#include <hip/hip_runtime.h>

typedef unsigned short u16;
typedef unsigned int u32;
typedef __attribute__((ext_vector_type(4))) unsigned short u16x4;
typedef __attribute__((ext_vector_type(8))) unsigned short u16x8;
typedef __attribute__((ext_vector_type(8))) __bf16 bf16x8;
typedef __attribute__((ext_vector_type(4))) float f32x4;
typedef __attribute__((ext_vector_type(16))) float f32x16;

#define SEQ 2048
#define DMODEL 1024
#define LDP 3072
#define MM (DMODEL * DMODEL)
#define SC 0.18033688f  // (1/8) * log2(e)

__device__ __forceinline__ u16 f2bf(float f) {
  unsigned u = __builtin_bit_cast(unsigned, f);
  u = (u + 0x7fffu + ((u >> 16) & 1u)) >> 16;
  return (u16)u;
}

__device__ __forceinline__ u32 cvtpk(float lo, float hi) {
  u32 r;
  asm volatile("v_cvt_pk_bf16_f32 %0, %1, %2" : "=v"(r) : "v"(lo), "v"(hi));
  return r;
}

__device__ __forceinline__ float fexp2(float x) {
#if __has_builtin(__builtin_amdgcn_exp2f)
  return __builtin_amdgcn_exp2f(x);
#else
  return exp2f(x);
#endif
}

__device__ __forceinline__ bf16x8 ldbf8(const u16* p) {
  return __builtin_bit_cast(bf16x8, *(const u16x8*)p);
}
__device__ __forceinline__ bf16x8 ldbf8c(const char* p) {
  return __builtin_bit_cast(bf16x8, *(const u16x8*)p);
}

__device__ __forceinline__ f32x4 mfma16(bf16x8 a, bf16x8 b, f32x4 c) {
  return __builtin_amdgcn_mfma_f32_16x16x32_bf16(a, b, c, 0, 0, 0);
}
__device__ __forceinline__ f32x16 mfma32(bf16x8 a, bf16x8 b, f32x16 c) {
  return __builtin_amdgcn_mfma_f32_32x32x16_bf16(a, b, c, 0, 0, 0);
}

__device__ __forceinline__ void gl16(const void* g, void* l) {
  __builtin_amdgcn_global_load_lds(
      (__attribute__((address_space(1))) void*)(size_t)g,
      (__attribute__((address_space(3))) void*)l, 16, 0, 0);
}

// ----------------- fp32 -> bf16 cast (single merged kernel) -----------------
__global__ void cast_all_k(const float* __restrict__ q, const float* __restrict__ k,
                           const float* __restrict__ v, const float* __restrict__ wq,
                           const float* __restrict__ wk, const float* __restrict__ wv,
                           const float* __restrict__ wo, u16* __restrict__ dq,
                           u16* __restrict__ dk, u16* __restrict__ dv,
                           u16* __restrict__ wqkv, u16* __restrict__ wob) {
  int b = blockIdx.x;
  const float* s;
  u16* d;
  if (b < 6144) {  // q,k,v: 2048 blocks each
    const int z = b >> 11;
    s = z == 0 ? q : z == 1 ? k : v;
    d = z == 0 ? dq : z == 1 ? dk : dv;
    b &= 2047;
  } else {  // weights: 512 blocks each
    const int z = (b - 6144) >> 9;
    s = z == 0 ? wq : z == 1 ? wk : z == 2 ? wv : wo;
    d = z < 3 ? wqkv + (size_t)z * MM : wob;
    b = (b - 6144) & 511;
  }
  const size_t i = ((size_t)b * blockDim.x + threadIdx.x) * 8;
  const float4 a = *(const float4*)(s + i);
  const float4 c = *(const float4*)(s + i + 4);
  u16x8 o;
  o[0] = f2bf(a.x); o[1] = f2bf(a.y); o[2] = f2bf(a.z); o[3] = f2bf(a.w);
  o[4] = f2bf(c.x); o[5] = f2bf(c.y); o[6] = f2bf(c.z); o[7] = f2bf(c.w);
  *(u16x8*)(d + i) = o;
}

// ----------------- GEMM: C = A @ B^T + bias (BK=64, swizzled gl16) ---------
// LDS arrays declared in the KERNEL and passed in (round-14 lesson: per-
// instantiation static __shared__ doubles LDS -> occupancy wall).
template <int OMODE>
__device__ __forceinline__ void gemm_bt_body(u16* __restrict__ As,
                                             u16* __restrict__ Bs,
                                             const u16* __restrict__ A,
                                             const u16* __restrict__ Bw,
                                             const float* __restrict__ bias,
                                             void* __restrict__ Cv, const int K,
                                             const int ldc, const int ncol0,
                                             const int m0, const int n0,
                                             const float osc) {
  const int tid = threadIdx.x;
  const int lane = tid & 63;
  const int w = tid >> 6;
  const int l15 = lane & 15;
  const int lg = lane >> 4;

  f32x4 acc[4][4] = {};

  const int arow = (w >> 1) * 64 + l15;
  const int brow = (w & 1) * 64 + l15;
  const int swz = (l15 & 7) << 4;

  const u16* Ags[4];
  const u16* Bgs[4];
#pragma unroll
  for (int j = 0; j < 4; ++j) {
    const int c = w * 64 + lane + j * 256;
    const int row = c >> 3;
    const int sc = ((c & 7) ^ (row & 7)) * 8;
    Ags[j] = A + (size_t)(m0 + row) * K + sc;
    Bgs[j] = Bw + (size_t)(n0 + row) * K + sc;
  }

  for (int k0 = 0; k0 < K; k0 += 64) {
    __syncthreads();  // prior iter's LDS reads done
#pragma unroll
    for (int j = 0; j < 4; ++j) {
      gl16(Ags[j] + k0, (char*)As + (w + j * 4) * 1024);
      gl16(Bgs[j] + k0, (char*)Bs + (w + j * 4) * 1024);
    }
    __syncthreads();  // barrier drains vmcnt -> staged data visible
#pragma unroll
    for (int kk = 0; kk < 2; ++kk) {
      const int cb = (kk * 64 + lg * 16) ^ swz;
      bf16x8 af[4], bfv[4];
#pragma unroll
      for (int t = 0; t < 4; ++t) {
        af[t] = ldbf8c((char*)As + (arow + t * 16) * 128 + cb);
        bfv[t] = ldbf8c((char*)Bs + (brow + t * 16) * 128 + cb);
      }
      __builtin_amdgcn_s_setprio(1);
#pragma unroll
      for (int i = 0; i < 4; ++i)
#pragma unroll
        for (int j = 0; j < 4; ++j) acc[i][j] = mfma16(af[i], bfv[j], acc[i][j]);
      __builtin_amdgcn_s_setprio(0);
    }
  }

  const int mrow = (w >> 1) * 64 + lg * 4;
  const int ncol = (w & 1) * 64 + l15;
#pragma unroll
  for (int j = 0; j < 4; ++j) {
    const int gn = n0 + ncol + j * 16;
    const float bia = bias[gn];
#pragma unroll
    for (int i = 0; i < 4; ++i) {
      const int gmb = m0 + mrow + i * 16;
#pragma unroll
      for (int r = 0; r < 4; ++r) {
        const float val = (acc[i][j][r] + bia) * osc;
        const int gm = gmb + r;
        if (OMODE == 0) {
          ((float*)Cv)[(size_t)gm * ldc + gn] = val;
        } else if (OMODE == 1) {
          ((u16*)Cv)[(size_t)gm * ldc + ncol0 + gn] = f2bf(val);
        } else {
          const int bb = gm >> 11, ss = gm & 2047;
          const int ssp = (ss & ~12) | ((ss & 4) << 1) | ((ss & 8) >> 1);
          const int hh = gn >> 6, dd = gn & 63;
          ((u16*)Cv)[(((size_t)(bb * 16 + hh) * 64 + dd) << 11) + ssp] = f2bf(val);
        }
      }
    }
  }
}

// XCD-chunked QKV projections (768 blocks; xcd = b&7).
__global__ __launch_bounds__(256, 3) void gemm_qkv_k(
    const u16* __restrict__ qb, const u16* __restrict__ kb,
    const u16* __restrict__ vb, const u16* __restrict__ wqkv,
    const float* __restrict__ bq, const float* __restrict__ bk,
    const float* __restrict__ bv, u16* __restrict__ proj, u16* __restrict__ vtb) {
  __shared__ u16 As[128 * 64];  // shared across both instantiations below
  __shared__ u16 Bs[128 * 64];
  const int b = blockIdx.x;
  const int xcd = b & 7;
  const int i = b >> 3;
  const int z = i >> 5;
  const int j = i & 31;
  const int m0 = (xcd * 4 + (j >> 3)) * 128;
  const int n0 = (j & 7) * 128;
  if (z == 2)
    gemm_bt_body<2>(As, Bs, vb, wqkv + 2 * (size_t)MM, bv, vtb, DMODEL, 0, 0,
                    m0, n0, 1.0f);
  else
    gemm_bt_body<1>(As, Bs, z == 0 ? qb : kb, wqkv + (size_t)z * MM,
                    z == 0 ? bq : bk, proj, DMODEL, LDP, z * DMODEL, m0, n0,
                    z == 0 ? SC : 1.0f);
}

__global__ __launch_bounds__(256, 3) void gemm_o_k(const u16* __restrict__ attnb,
                                                   const u16* __restrict__ wob,
                                                   const float* __restrict__ bo,
                                                   float* __restrict__ out) {
  __shared__ u16 As[128 * 64];
  __shared__ u16 Bs[128 * 64];
  const int b = blockIdx.x;
  const int xcd = b & 7;
  const int i = b >> 3;
  const int m0 = (xcd * 4 + (i >> 3)) * 128;
  const int n0 = (i & 7) * 128;
  gemm_bt_body<0>(As, Bs, attnb, wob, bo, out, DMODEL, DMODEL, 0, m0, n0, 1.0f);
}

// ----------------- flash attention: split-KV, q-reuse, gl16 staging --------
// 256 blocks x 512 threads (1/CU). 2 kv-groups x 4 waves; wave owns 64 q
// (2 tiles), 16 iters of 64 kv. Staging = global_load_lds with PRE-SWIZZLED
// per-lane sources (linear LDS dest + inverse-swz source + swz read). V^T
// stored column-permuted (bit2<->3 per 16-group) so PV A-frags are single
// ds_read_b128 under the K-style swizzle.
__global__ __launch_bounds__(512, 2) void attn_k(const u16* __restrict__ proj,
                                                 const u16* __restrict__ vtb,
                                                 u16* __restrict__ outa) {
  __shared__ __align__(16) char smem[65536];
  const int b = blockIdx.x;
  const int slot = b >> 3;                 // 0..31
  const int bh = (b & 7) * 4 + (slot >> 3);
  const int qB = (slot & 7) * 256;
  const int tid = threadIdx.x;
  const int lane = tid & 63;
  const int w = tid >> 6;
  const int g = w >> 2;        // kv-half group
  const int wg = w & 3;        // wave within group
  const size_t rb = (size_t)(bh >> 4) * SEQ;
  const int h = bh & 15;
  const int l31 = lane & 31;
  const int hi = lane >> 5;
  const int swzk = (l31 & 7) << 4;

  // LDS: group g at g*32768: K[p] at p*8192, V[p] at 16384 + p*8192
  char* const gbase = smem + g * 32768;

  // Q B-frags for both q-tiles (pre-scaled by SC)
  const int qW = qB + wg * 64;
  const u16* qpA = proj + (rb + qW + l31) * LDP + h * 64 + hi * 8;
  const u16* qpB = qpA + (size_t)32 * LDP;
  bf16x8 qfA[4], qfB[4];
#pragma unroll
  for (int km = 0; km < 4; ++km) {
    qfA[km] = ldbf8(qpA + km * 16);
    qfB[km] = ldbf8(qpB + km * 16);
  }

  // staging constants (pre-swizzled source; linear LDS dest)
  const int cxe = ((lane & 7) ^ (lane >> 3)) * 8;  // element offset
  const int row0 = wg * 16 + (lane >> 3);          // j=0 row
  const int row1 = row0 + 8;                       // j=1 row
  const u16* kg = proj + rb * LDP + DMODEL + h * 64;  // K rows, stride LDP
  const u16* vg = vtb + (size_t)bh * 64 * SEQ;        // V^T rows [d][s-perm]
  const int kvbase = g * (SEQ / 2);
  const u16* ks0 = kg + (size_t)(kvbase + row0) * LDP + cxe;
  const u16* ks1 = kg + (size_t)(kvbase + row1) * LDP + cxe;
  const u16* vs0 = vg + (size_t)row0 * SEQ + kvbase + cxe;
  const u16* vs1 = vg + (size_t)row1 * SEQ + kvbase + cxe;

#define STAGE(P, KOFF)                                                   \
  {                                                                      \
    char* kb_ = gbase + (P) * 8192;                                      \
    char* vb_ = gbase + 16384 + (P) * 8192;                              \
    gl16(ks0 + (size_t)(KOFF) * LDP, kb_ + (wg * 2 + 0) * 1024);         \
    gl16(ks1 + (size_t)(KOFF) * LDP, kb_ + (wg * 2 + 1) * 1024);         \
    gl16(vs0 + (KOFF), vb_ + (wg * 2 + 0) * 1024);                       \
    gl16(vs1 + (KOFF), vb_ + (wg * 2 + 1) * 1024);                       \
  }

  f32x16 oaA0 = {}, oaA1 = {}, oaB0 = {}, oaB1 = {};
  float lrunA = 0.f, lrunB = 0.f;
  int p = 0;

  STAGE(0, 0);
  __syncthreads();

  for (int it = 0; it < SEQ / 128; ++it) {  // 16 tiles per group
    if (it + 1 < SEQ / 128) STAGE(p ^ 1, (it + 1) * 64);
    // ---- QK^T: each K-frag feeds both q-tiles ----
    const char* kp = gbase + p * 8192;
    const char* vp = gbase + 16384 + p * 8192;
    f32x16 sA0 = {}, sA1 = {}, sB0 = {}, sB1 = {};
    __builtin_amdgcn_s_setprio(1);
#pragma unroll
    for (int km = 0; km < 4; ++km) {
      const int co = (km * 32 + hi * 16) ^ swzk;
      const bf16x8 k0 = ldbf8c(kp + l31 * 128 + co);
      const bf16x8 k1 = ldbf8c(kp + (32 + l31) * 128 + co);
      sA0 = mfma32(k0, qfA[km], sA0);
      sB0 = mfma32(k0, qfB[km], sB0);
      sA1 = mfma32(k1, qfA[km], sA1);
      sB1 = mfma32(k1, qfB[km], sB1);
    }
    __builtin_amdgcn_s_setprio(0);

    // ---- P = exp2(s); unnormalized row sums ----
#pragma unroll
    for (int r = 0; r < 16; ++r) sA0[r] = fexp2(sA0[r]);
#pragma unroll
    for (int r = 0; r < 16; ++r) sA1[r] = fexp2(sA1[r]);
#pragma unroll
    for (int r = 0; r < 16; ++r) sB0[r] = fexp2(sB0[r]);
#pragma unroll
    for (int r = 0; r < 16; ++r) sB1[r] = fexp2(sB1[r]);
#define SUM16(V)                                                        \
    ((((V[0] + V[1]) + (V[2] + V[3])) + ((V[4] + V[5]) + (V[6] + V[7]))) + \
     (((V[8] + V[9]) + (V[10] + V[11])) + ((V[12] + V[13]) + (V[14] + V[15]))))
    float rsA = SUM16(sA0) + SUM16(sA1);
    float rsB = SUM16(sB0) + SUM16(sB1);
#undef SUM16
    rsA += __shfl_xor(rsA, 32);
    rsB += __shfl_xor(rsB, 32);
    lrunA += rsA;
    lrunB += rsB;

    // ---- PV: V frags are b128 (permuted storage); feed both q-tiles ----
    __builtin_amdgcn_s_setprio(1);
#define PCHUNK2(SA, SB, G, M)                                            \
    {                                                                    \
      u16x8 pbuA, pbuB;                                                  \
      ((u32*)&pbuA)[0] = cvtpk(SA[G + 0], SA[G + 1]);                    \
      ((u32*)&pbuA)[1] = cvtpk(SA[G + 2], SA[G + 3]);                    \
      ((u32*)&pbuA)[2] = cvtpk(SA[G + 4], SA[G + 5]);                    \
      ((u32*)&pbuA)[3] = cvtpk(SA[G + 6], SA[G + 7]);                    \
      ((u32*)&pbuB)[0] = cvtpk(SB[G + 0], SB[G + 1]);                    \
      ((u32*)&pbuB)[1] = cvtpk(SB[G + 2], SB[G + 3]);                    \
      ((u32*)&pbuB)[2] = cvtpk(SB[G + 4], SB[G + 5]);                    \
      ((u32*)&pbuB)[3] = cvtpk(SB[G + 6], SB[G + 7]);                    \
      const bf16x8 pbA = __builtin_bit_cast(bf16x8, pbuA);               \
      const bf16x8 pbB = __builtin_bit_cast(bf16x8, pbuB);               \
      const int vc = ((M) * 32 + hi * 16) ^ swzk;                        \
      const bf16x8 v0 = ldbf8c(vp + l31 * 128 + vc);                     \
      const bf16x8 v1 = ldbf8c(vp + (32 + l31) * 128 + vc);              \
      oaA0 = mfma32(v0, pbA, oaA0);                                      \
      oaB0 = mfma32(v0, pbB, oaB0);                                      \
      oaA1 = mfma32(v1, pbA, oaA1);                                      \
      oaB1 = mfma32(v1, pbB, oaB1);                                      \
    }
    PCHUNK2(sA0, sB0, 0, 0)
    PCHUNK2(sA0, sB0, 8, 1)
    PCHUNK2(sA1, sB1, 0, 2)
    PCHUNK2(sA1, sB1, 8, 3)
#undef PCHUNK2
    __builtin_amdgcn_s_setprio(0);
    __syncthreads();  // drains vmcnt (next tile landed) + read/write fence
    p ^= 1;
  }
#undef STAGE

  // ---- two-pass merge of group B into group A (exact: pure adds) ----
  float* sc = (float*)smem;
  const int col = wg * 64 + lane;  // 0..255 within group
  if (g == 1) {
#pragma unroll
    for (int r = 0; r < 16; ++r) sc[r * 256 + col] = oaA0[r];
#pragma unroll
    for (int r = 0; r < 16; ++r) sc[(16 + r) * 256 + col] = oaA1[r];
    sc[32 * 256 + col] = lrunA;
  }
  __syncthreads();
  if (g == 0) {
#pragma unroll
    for (int r = 0; r < 16; ++r) oaA0[r] += sc[r * 256 + col];
#pragma unroll
    for (int r = 0; r < 16; ++r) oaA1[r] += sc[(16 + r) * 256 + col];
    lrunA += sc[32 * 256 + col];
  }
  __syncthreads();
  if (g == 1) {
#pragma unroll
    for (int r = 0; r < 16; ++r) sc[r * 256 + col] = oaB0[r];
#pragma unroll
    for (int r = 0; r < 16; ++r) sc[(16 + r) * 256 + col] = oaB1[r];
    sc[32 * 256 + col] = lrunB;
  }
  __syncthreads();
  if (g == 0) {
#pragma unroll
    for (int r = 0; r < 16; ++r) oaB0[r] += sc[r * 256 + col];
#pragma unroll
    for (int r = 0; r < 16; ++r) oaB1[r] += sc[(16 + r) * 256 + col];
    lrunB += sc[32 * 256 + col];

    // ---- epilogue: O^T[d][q] -> attnb[q][h*64+d], both q-tiles ----
    const float invA = 1.0f / lrunA;
    u16* orowA = outa + (rb + qW + l31) * DMODEL + h * 64 + hi * 4;
#pragma unroll
    for (int gg = 0; gg < 4; ++gg) {
      u16x4 st0, st1;
      ((u32*)&st0)[0] = cvtpk(oaA0[4 * gg + 0] * invA, oaA0[4 * gg + 1] * invA);
      ((u32*)&st0)[1] = cvtpk(oaA0[4 * gg + 2] * invA, oaA0[4 * gg + 3] * invA);
      *(u16x4*)(orowA + 8 * gg) = st0;
      ((u32*)&st1)[0] = cvtpk(oaA1[4 * gg + 0] * invA, oaA1[4 * gg + 1] * invA);
      ((u32*)&st1)[1] = cvtpk(oaA1[4 * gg + 2] * invA, oaA1[4 * gg + 3] * invA);
      *(u16x4*)(orowA + 32 + 8 * gg) = st1;
    }
    const float invB = 1.0f / lrunB;
    u16* orowB = orowA + (size_t)32 * DMODEL;
#pragma unroll
    for (int gg = 0; gg < 4; ++gg) {
      u16x4 st0, st1;
      ((u32*)&st0)[0] = cvtpk(oaB0[4 * gg + 0] * invB, oaB0[4 * gg + 1] * invB);
      ((u32*)&st0)[1] = cvtpk(oaB0[4 * gg + 2] * invB, oaB0[4 * gg + 3] * invB);
      *(u16x4*)(orowB + 8 * gg) = st0;
      ((u32*)&st1)[0] = cvtpk(oaB1[4 * gg + 0] * invB, oaB1[4 * gg + 1] * invB);
      ((u32*)&st1)[1] = cvtpk(oaB1[4 * gg + 2] * invB, oaB1[4 * gg + 3] * invB);
      *(u16x4*)(orowB + 32 + 8 * gg) = st1;
    }
  }
}

extern "C" void kernel_launch(void* const* d_in, const int* in_sizes, int n_in,
                              void* d_out, int out_size, void* d_ws, size_t ws_size,
                              hipStream_t stream) {
  const float* q  = (const float*)d_in[0];
  const float* k  = (const float*)d_in[1];
  const float* v  = (const float*)d_in[2];
  const float* wq = (const float*)d_in[3];
  const float* bq = (const float*)d_in[4];
  const float* wk = (const float*)d_in[5];
  const float* bk = (const float*)d_in[6];
  const float* wv = (const float*)d_in[7];
  const float* bv = (const float*)d_in[8];
  const float* wo = (const float*)d_in[9];
  const float* bo = (const float*)d_in[10];

  const size_t NTOK = (size_t)2 * SEQ;
  const size_t NELE = NTOK * DMODEL;
  u16* qb    = (u16*)d_ws;
  u16* kb    = qb + NELE;
  u16* vb    = kb + NELE;
  u16* wqkv  = vb + NELE;
  u16* wob   = wqkv + 3 * (size_t)MM;
  u16* projb = wob + (size_t)MM;          // [4096][3072] bf16 (Q,K sections)
  u16* vtb   = projb + NTOK * LDP;        // [32 bh][64 d][2048 s-perm] bf16
  u16* attnb = qb;  // qb dead after projections -> reuse

  cast_all_k<<<8192, 256, 0, stream>>>(q, k, v, wq, wk, wv, wo, qb, kb, vb,
                                       wqkv, wob);
  gemm_qkv_k<<<768, 256, 0, stream>>>(qb, kb, vb, wqkv, bq, bk, bv, projb, vtb);
  attn_k<<<256, 512, 0, stream>>>(projb, vtb, attnb);
  gemm_o_k<<<256, 256, 0, stream>>>(attnb, wob, bo, (float*)d_out);
}